// Round 4
// baseline (841.542 us; speedup 1.0000x reference)
//
#include <hip/hip_runtime.h>
#include <hip/hip_bf16.h>

#define BB 8
#define TT 168
#define NN 425
#define EE 2048
#define II 128
#define HH 256
#define F1 10
#define F2 32
#define BT (BB*TT)       // 1344
#define K2 (NN*F2)       // 13600
#define N2 (2*NN)        // 850

// LSTM: 512 thr/block, thread owns 2 rows. Per row: 112 h2 in VGPRs
// (2x112=224 regs), 16 h2 in LDS (64 KB/block). h broadcast via readlane.
#define RJ2 112                 // h2 per row in registers (k2 in [0,112))
#define RJ8 28                  // h8 chunks per row in regs
#define WREG8 (512*2*RJ8)       // 28672 h8
#define WLDS8 (2*4*512)         // 4096 h8 = 64 KB

typedef _Float16 h2 __attribute__((ext_vector_type(2)));
typedef _Float16 h8 __attribute__((ext_vector_type(8)));
typedef short bf16x8 __attribute__((ext_vector_type(8)));
typedef float f32x4 __attribute__((ext_vector_type(4)));

__device__ __forceinline__ float relu_(float x){ return fmaxf(x, 0.f); }
__device__ __forceinline__ float sigmoid_(float x){ return 1.f/(1.f + expf(-x)); }
__device__ __forceinline__ float dot2_(h2 a, h2 b, float c){
#if __has_builtin(__builtin_amdgcn_fdot2)
    return __builtin_amdgcn_fdot2(a, b, c, false);
#else
    return c + (float)a[0]*(float)b[0] + (float)a[1]*(float)b[1];
#endif
}

// ---------------- GCN: two layers fused, one block per (b,t) graph ----------
__global__ __launch_bounds__(256) void gcn_kernel(
    const float* __restrict__ nf, const int* __restrict__ esrc,
    const int* __restrict__ edst, const float* __restrict__ ew,
    const float* __restrict__ Wg1, const float* __restrict__ bg1,
    const float* __restrict__ Wg2, const float* __restrict__ bg2,
    __hip_bfloat16* __restrict__ x2g)
{
    __shared__ float xs[NN];
    __shared__ float dinv[NN];
    __shared__ float agg1[NN];
    __shared__ float nrm[EE];
    __shared__ float x1[NN*F1];
    __shared__ float agg2[NN*F1];
    __shared__ float wg1s[F1], bg1s[F1], wg2s[F1*F2], bg2s[F2];

    const int bt = blockIdx.x, tid = threadIdx.x;
    const long eb = (long)bt * EE;

    for (int v = tid; v < NN; v += 256) {
        xs[v] = nf[(long)bt*NN + v];
        dinv[v] = 1.0f;
        agg1[v] = 0.f;
    }
    for (int i = tid; i < NN*F1; i += 256) agg2[i] = 0.f;
    if (tid < F1) { wg1s[tid] = Wg1[tid]; bg1s[tid] = bg1[tid]; }
    if (tid < F2) bg2s[tid] = bg2[tid];
    for (int i = tid; i < F1*F2; i += 256) wg2s[i] = Wg2[i];
    __syncthreads();

    for (int e = tid; e < EE; e += 256)
        atomicAdd(&dinv[edst[eb+e]], ew[eb+e]);
    __syncthreads();
    for (int v = tid; v < NN; v += 256) {
        float dg = dinv[v];
        dinv[v] = dg > 0.f ? 1.0f / sqrtf(fmaxf(dg, 1e-12f)) : 0.f;
    }
    __syncthreads();

    for (int e = tid; e < EE; e += 256) {
        int s = esrc[eb+e], d = edst[eb+e];
        float nm = dinv[s] * ew[eb+e] * dinv[d];
        nrm[e] = nm;
        atomicAdd(&agg1[d], nm * xs[s]);
    }
    __syncthreads();
    for (int v = tid; v < NN; v += 256) agg1[v] += dinv[v]*dinv[v]*xs[v];
    __syncthreads();
    for (int i = tid; i < NN*F1; i += 256) {
        int v = i / F1, f = i - v*F1;
        x1[i] = relu_(agg1[v] * wg1s[f] + bg1s[f]);
    }
    __syncthreads();

    for (int e = tid; e < EE; e += 256) {
        int s = esrc[eb+e], d = edst[eb+e];
        float nm = nrm[e];
        #pragma unroll
        for (int f = 0; f < F1; ++f)
            atomicAdd(&agg2[d*F1+f], nm * x1[s*F1+f]);
    }
    __syncthreads();
    for (int i = tid; i < NN*F1; i += 256) {
        int v = i / F1;
        agg2[i] += dinv[v]*dinv[v]*x1[i];
    }
    __syncthreads();

    for (int i = tid; i < NN*F2; i += 256) {
        int v = i >> 5, k = i & 31;
        float o = bg2s[k];
        #pragma unroll
        for (int f = 0; f < F1; ++f) o += agg2[v*F1+f] * wg2s[f*F2+k];
        x2g[(long)bt*K2 + i] = __float2bfloat16(relu_(o));
    }
}

// ---------------- transpose-pack Wgfc fp32 [13600,128] -> bf16 [128,13600] --
__global__ __launch_bounds__(256) void packT_kernel(
    const float* __restrict__ W, __hip_bfloat16* __restrict__ out)
{
    __shared__ float tile[64][129];
    const int k0 = blockIdx.x * 64, tid = threadIdx.x;
    for (int i = tid; i < 64*128; i += 256) {
        int r = i >> 7, j = i & 127;
        tile[r][j] = (k0 + r < K2) ? W[(size_t)(k0+r)*II + j] : 0.f;
    }
    __syncthreads();
    for (int i = tid; i < 64*128; i += 256) {
        int j = i >> 6, r = i & 63;
        if (k0 + r < K2) out[(size_t)j*K2 + k0 + r] = __float2bfloat16(tile[r][j]);
    }
}

// ---------------- MFMA bf16 GEMM: g_pre = x2 @ Wgfc ------------------------
// A [1344,13600] bf16 row-major; BT_ = Wgfc^T [128,13600] bf16 row-major.
#define GBM 64
#define GBK 64
#define GNT 213   // ceil(13600/64)
__global__ __launch_bounds__(512) void gemm_kernel(
    const __hip_bfloat16* __restrict__ A, const __hip_bfloat16* __restrict__ Bt,
    float* __restrict__ C)
{
    __shared__ __align__(16) char As[2][GBM*GBK*2];    // 8 KB x2
    __shared__ __align__(16) char Bs[2][II*GBK*2];     // 16 KB x2
    const int tid = threadIdx.x;
    const int row0 = blockIdx.x * GBM;
    const int wave = tid >> 6, lane = tid & 63;
    const int wm = wave >> 2, wn = wave & 3;
    const int l16 = lane & 15, lk = lane >> 4;
    const short* Aa = (const short*)A;
    const short* Bb = (const short*)Bt;

    const int ar = tid >> 3, ac = tid & 7;        // A: row 0..63, chunk 0..7
    const int bc = tid >> 2, bh = (tid & 3) * 2;  // B: col 0..127, chunks bh,bh+1

    f32x4 acc[2][2];
    #pragma unroll
    for (int m = 0; m < 2; ++m)
        #pragma unroll
        for (int n = 0; n < 2; ++n) acc[m][n] = (f32x4){0.f,0.f,0.f,0.f};

    // stage tile 0
    {
        bf16x8 a0 = {0,0,0,0,0,0,0,0}, b0 = a0, b1 = a0;
        if (ac*8 < K2)      a0 = *(const bf16x8*)(Aa + (size_t)(row0+ar)*K2 + ac*8);
        if (bh*8 < K2)      b0 = *(const bf16x8*)(Bb + (size_t)bc*K2 + bh*8);
        if ((bh+1)*8 < K2)  b1 = *(const bf16x8*)(Bb + (size_t)bc*K2 + (bh+1)*8);
        *(bf16x8*)(&As[0][0] + ((ar*128 + ac*16) ^ ((ar&7)<<4))) = a0;
        *(bf16x8*)(&Bs[0][0] + ((bc*128 + bh*16) ^ ((bc&7)<<4))) = b0;
        *(bf16x8*)(&Bs[0][0] + ((bc*128 + (bh+1)*16) ^ ((bc&7)<<4))) = b1;
    }
    __syncthreads();

    for (int s = 0; s < GNT; ++s) {
        const int d = s & 1;
        bf16x8 a0 = {0,0,0,0,0,0,0,0}, b0 = a0, b1 = a0;
        if (s + 1 < GNT) {
            int k0n = (s+1)*GBK;
            if (k0n + ac*8 < K2)     a0 = *(const bf16x8*)(Aa + (size_t)(row0+ar)*K2 + k0n + ac*8);
            if (k0n + bh*8 < K2)     b0 = *(const bf16x8*)(Bb + (size_t)bc*K2 + k0n + bh*8);
            if (k0n + (bh+1)*8 < K2) b1 = *(const bf16x8*)(Bb + (size_t)bc*K2 + k0n + (bh+1)*8);
        }
        #pragma unroll
        for (int s2 = 0; s2 < 2; ++s2) {
            bf16x8 af[2], bf[2];
            #pragma unroll
            for (int m = 0; m < 2; ++m) {
                int row = wm*32 + m*16 + l16;
                af[m] = *(const bf16x8*)(&As[d][0] + ((row*128 + s2*64 + lk*16) ^ ((row&7)<<4)));
            }
            #pragma unroll
            for (int n = 0; n < 2; ++n) {
                int col = wn*32 + n*16 + l16;
                bf[n] = *(const bf16x8*)(&Bs[d][0] + ((col*128 + s2*64 + lk*16) ^ ((col&7)<<4)));
            }
            #pragma unroll
            for (int m = 0; m < 2; ++m)
                #pragma unroll
                for (int n = 0; n < 2; ++n)
                    acc[m][n] = __builtin_amdgcn_mfma_f32_16x16x32_bf16(af[m], bf[n], acc[m][n], 0, 0, 0);
        }
        if (s + 1 < GNT) {
            *(bf16x8*)(&As[d^1][0] + ((ar*128 + ac*16) ^ ((ar&7)<<4))) = a0;
            *(bf16x8*)(&Bs[d^1][0] + ((bc*128 + bh*16) ^ ((bc&7)<<4))) = b0;
            *(bf16x8*)(&Bs[d^1][0] + ((bc*128 + (bh+1)*16) ^ ((bc&7)<<4))) = b1;
        }
        __syncthreads();
    }

    #pragma unroll
    for (int m = 0; m < 2; ++m)
        #pragma unroll
        for (int n = 0; n < 2; ++n)
            #pragma unroll
            for (int q = 0; q < 4; ++q)
                C[(size_t)(row0 + wm*32 + m*16 + lk*4 + q)*II + wn*32 + n*16 + l16] = acc[m][n][q];
}

// ---------------- infect & temp MLP branches (16 rows per block) ------------
__global__ __launch_bounds__(256) void branches_kernel(
    const float* __restrict__ infect, const float* __restrict__ temp,
    const float* __restrict__ Wi1, const float* __restrict__ bi1,
    const float* __restrict__ Wi2, const float* __restrict__ bi2,
    const float* __restrict__ Wi3, const float* __restrict__ bi3,
    const float* __restrict__ Wi4, const float* __restrict__ bi4,
    const float* __restrict__ Wt1, const float* __restrict__ bt1,
    const float* __restrict__ Wt2, const float* __restrict__ bt2,
    float* __restrict__ infout, float* __restrict__ tpout)
{
    __shared__ float inA[16*25], inT[16*13];
    __shared__ float bufA[16*II], bufB[16*II];
    const int r0 = blockIdx.x * 16, tid = threadIdx.x;

    for (int i = tid; i < 16*25; i += 256) { int r=i/25,k=i-r*25; inA[i] = infect[(long)(r0+r)*25+k]; }
    for (int i = tid; i < 16*13; i += 256) { int r=i/13,k=i-r*13; inT[i] = temp[(long)(r0+r)*13+k]; }
    __syncthreads();
    for (int i = tid; i < 16*II; i += 256) { int r=i>>7,u=i&127; float o=bi1[u];
        for (int k=0;k<25;++k) o += inA[r*25+k]*Wi1[k*II+u];
        bufA[i]=relu_(o); }
    __syncthreads();
    for (int i = tid; i < 16*II; i += 256) { int r=i>>7,u=i&127; float o=bi2[u];
        for (int k=0;k<II;++k) o += bufA[r*II+k]*Wi2[k*II+u];
        bufB[i]=relu_(o); }
    __syncthreads();
    for (int i = tid; i < 16*64; i += 256) { int r=i>>6,u=i&63; float o=bi3[u];
        for (int k=0;k<II;++k) o += bufB[r*II+k]*Wi3[k*64+u];
        bufA[r*64+u]=relu_(o); }
    __syncthreads();
    for (int i = tid; i < 16*II; i += 256) { int r=i>>7,u=i&127; float o=bi4[u];
        for (int k=0;k<64;++k) o += bufA[r*64+k]*Wi4[k*II+u];
        infout[(long)(r0+r)*II+u]=relu_(o); }
    for (int i = tid; i < 16*64; i += 256) { int r=i>>6,u=i&63; float o=bt1[u];
        for (int k=0;k<13;++k) o += inT[r*13+k]*Wt1[k*64+u];
        bufB[r*64+u]=relu_(o); }
    __syncthreads();
    for (int i = tid; i < 16*II; i += 256) { int r=i>>7,u=i&127; float o=bt2[u];
        for (int k=0;k<64;++k) o += bufB[r*64+k]*Wt2[k*II+u];
        tpout[(long)(r0+r)*II+u]=relu_(o); }
}

// ---------------- li = relu(cat@Wcat+bcat); xg = li@Wih^T + bih + bhh -------
__global__ __launch_bounds__(256) void li_xg_kernel(
    const float* __restrict__ g_pre, const float* __restrict__ bgfc,
    const float* __restrict__ infb, const float* __restrict__ tpb,
    const float* __restrict__ Wcat, const float* __restrict__ bcat,
    const float* __restrict__ Wih, const float* __restrict__ bih,
    const float* __restrict__ bhh, float* __restrict__ xg)
{
    __shared__ float cat[16*384];
    __shared__ __align__(16) float li[16*II];
    const int r0 = blockIdx.x * 16, tid = threadIdx.x;

    for (int i = tid; i < 16*II; i += 256) {
        int r = i>>7, u = i&127;
        cat[r*384 + u]       = relu_(g_pre[(long)(r0+r)*II+u] + bgfc[u]);
        cat[r*384 + 128 + u] = infb[(long)(r0+r)*II+u];
        cat[r*384 + 256 + u] = tpb[(long)(r0+r)*II+u];
    }
    __syncthreads();
    {
        int u = tid & 127, rh = tid >> 7;
        float acc[8];
        #pragma unroll
        for (int x = 0; x < 8; ++x) acc[x] = bcat[u];
        for (int k = 0; k < 384; ++k) {
            float w = Wcat[k*II+u];
            #pragma unroll
            for (int x = 0; x < 8; ++x) acc[x] += cat[(rh*8+x)*384 + k] * w;
        }
        #pragma unroll
        for (int x = 0; x < 8; ++x) li[(rh*8+x)*II + u] = relu_(acc[x]);
    }
    __syncthreads();
    for (int jj = 0; jj < 4; ++jj) {
        int j = tid + jj*256;
        float bb = bih[j] + bhh[j];
        float acc[16];
        #pragma unroll
        for (int r = 0; r < 16; ++r) acc[r] = bb;
        for (int k4 = 0; k4 < 32; ++k4) {
            float4 wv = *(const float4*)&Wih[(long)j*II + k4*4];
            #pragma unroll
            for (int r = 0; r < 16; ++r) {
                float4 lv = *(const float4*)&li[r*II + k4*4];
                acc[r] += wv.x*lv.x + wv.y*lv.y + wv.z*lv.z + wv.w*lv.w;
            }
        }
        #pragma unroll
        for (int r = 0; r < 16; ++r) xg[(long)(r0+r)*1024 + j] = acc[r];
    }
}

// ---------------- pack Whh fp32 -> fp16 register/LDS layouts ----------------
// Thread u owns rows R0=(u>>8)*512+(u&255), R0+256.
// wreg8[u*56 + r*28 + m] : h8 = k2 range [4m, 4m+4)  of row r
// wlds8[(r*4+c)*512 + u] : h8 = k2 range [112+4c, 112+4c+4)
__global__ __launch_bounds__(256) void pack_whh_kernel(
    const float* __restrict__ Whh, h8* __restrict__ wreg8,
    h8* __restrict__ wlds8)
{
    int i = blockIdx.x*256 + threadIdx.x;   // grid 128 blocks -> 32768
    int row, k2base;
    bool isreg = (i < WREG8);
    if (isreg) {
        int u = i / 56, rem = i % 56, r = rem / 28, m = rem % 28;
        row = ((u>>8)*2 + r)*256 + (u&255);
        k2base = m*4;
    } else {
        int L = i - WREG8;
        int u = L & 511, rc = L >> 9, c = rc & 3, r = rc >> 2;
        row = ((u>>8)*2 + r)*256 + (u&255);
        k2base = RJ2 + c*4;
    }
    h8 v;
    #pragma unroll
    for (int q = 0; q < 4; ++q) {
        v[2*q]   = (_Float16)Whh[(long)row*HH + 2*(k2base+q)];
        v[2*q+1] = (_Float16)Whh[(long)row*HH + 2*(k2base+q) + 1];
    }
    if (isreg) wreg8[i] = v; else wlds8[i - WREG8] = v;
}

// ---------------- LSTM: 1 block/batch, reg-resident Whh, readlane h bcast ---
__global__ __launch_bounds__(512, 2) void lstm_kernel(
    const float* __restrict__ xg, const h8* __restrict__ wreg8,
    const h8* __restrict__ wlds8, const float* __restrict__ h0,
    const float* __restrict__ c0, float* __restrict__ hbuf)
{
    const int u = threadIdx.x;
    const int v = u & 255;
    const int lane = u & 63;
    const int b = blockIdx.x;
    const int R0 = (u >> 8)*512 + v;

    __shared__ __align__(16) _Float16 harr[2][HH];
    __shared__ __align__(16) h8 wlds[WLDS8];     // 64 KB
    __shared__ float2 gex[256];

    for (int i = u; i < WLDS8; i += 512) wlds[i] = wlds8[i];

    h8 wreg[2*RJ8];                              // 56 h8 = 224 VGPRs
    {
        const h8* wp = wreg8 + (size_t)u * (2*RJ8);
        #pragma unroll
        for (int m = 0; m < 2*RJ8; ++m) wreg[m] = wp[m];
        #pragma unroll
        for (int m = 0; m < 2*RJ8; ++m) {
            float4 tmp = __builtin_bit_cast(float4, wreg[m]);
            asm volatile("" : "+v"(tmp.x), "+v"(tmp.y), "+v"(tmp.z), "+v"(tmp.w));
            wreg[m] = __builtin_bit_cast(h8, tmp);
        }
    }

    float c = 0.f;
    if (u < 256) { c = c0[b*HH + v]; harr[0][v] = (_Float16)h0[b*HH + v]; }
    __syncthreads();

    const float* xgb = xg + (size_t)b*TT*1024;
    float h_last = 0.f;

    #pragma unroll 1
    for (int t = 0; t < TT; ++t) {
        const int cb = t & 1;
        float x0 = xgb[t*1024 + R0];
        float x1 = xgb[t*1024 + R0 + 256];
        unsigned long long hv = *(const unsigned long long*)&harr[cb][4*lane];
        int hlo = (int)(unsigned int)hv;
        int hhi = (int)(hv >> 32);
        float a00 = 0.f, a01 = 0.f, a10 = 0.f, a11 = 0.f;

        // register-resident part: k2 in [0,112), lanes L = 0..55
        #pragma unroll
        for (int m = 0; m < RJ8; ++m) {
            h8 w0 = wreg[m];
            h8 w1 = wreg[RJ8 + m];
            int L = 2*m;
            h2 slo = __builtin_bit_cast(h2, __builtin_amdgcn_readlane(hlo, L));
            h2 shi = __builtin_bit_cast(h2, __builtin_amdgcn_readlane(hhi, L));
            a00 = dot2_(__builtin_shufflevector(w0, w0, 0, 1), slo, a00);
            a01 = dot2_(__builtin_shufflevector(w0, w0, 2, 3), shi, a01);
            a10 = dot2_(__builtin_shufflevector(w1, w1, 0, 1), slo, a10);
            a11 = dot2_(__builtin_shufflevector(w1, w1, 2, 3), shi, a11);
            slo = __builtin_bit_cast(h2, __builtin_amdgcn_readlane(hlo, L+1));
            shi = __builtin_bit_cast(h2, __builtin_amdgcn_readlane(hhi, L+1));
            a00 = dot2_(__builtin_shufflevector(w0, w0, 4, 5), slo, a00);
            a01 = dot2_(__builtin_shufflevector(w0, w0, 6, 7), shi, a01);
            a10 = dot2_(__builtin_shufflevector(w1, w1, 4, 5), slo, a10);
            a11 = dot2_(__builtin_shufflevector(w1, w1, 6, 7), shi, a11);
        }
        // LDS part: k2 in [112,128), lanes L = 56..63 (opaque addr: no LICM)
        #pragma unroll
        for (int cc = 0; cc < 4; ++cc) {
            unsigned off = (unsigned)((cc*512 + u) * 16);
            asm volatile("" : "+v"(off));
            h8 w0 = *(const h8*)((const char*)wlds + off);
            h8 w1 = *(const h8*)((const char*)wlds + off + 4*512*16);
            int L = 56 + 2*cc;
            h2 slo = __builtin_bit_cast(h2, __builtin_amdgcn_readlane(hlo, L));
            h2 shi = __builtin_bit_cast(h2, __builtin_amdgcn_readlane(hhi, L));
            a00 = dot2_(__builtin_shufflevector(w0, w0, 0, 1), slo, a00);
            a01 = dot2_(__builtin_shufflevector(w0, w0, 2, 3), shi, a01);
            a10 = dot2_(__builtin_shufflevector(w1, w1, 0, 1), slo, a10);
            a11 = dot2_(__builtin_shufflevector(w1, w1, 2, 3), shi, a11);
            slo = __builtin_bit_cast(h2, __builtin_amdgcn_readlane(hlo, L+1));
            shi = __builtin_bit_cast(h2, __builtin_amdgcn_readlane(hhi, L+1));
            a00 = dot2_(__builtin_shufflevector(w0, w0, 4, 5), slo, a00);
            a01 = dot2_(__builtin_shufflevector(w0, w0, 6, 7), shi, a01);
            a10 = dot2_(__builtin_shufflevector(w1, w1, 4, 5), slo, a10);
            a11 = dot2_(__builtin_shufflevector(w1, w1, 6, 7), shi, a11);
        }

        float g0 = a00 + a01 + x0;   // i (u<256) / g (u>=256)
        float g1 = a10 + a11 + x1;   // f (u<256) / o (u>=256)
        if (u >= 256) gex[v] = make_float2(g0, g1);
        __syncthreads();
        if (u < 256) {
            float2 ggo = gex[v];
            c = sigmoid_(g1)*c + sigmoid_(g0)*tanhf(ggo.x);
            float h = sigmoid_(ggo.y)*tanhf(c);
            harr[cb^1][v] = (_Float16)h;
            h_last = h;
        }
        __syncthreads();
    }
    if (u < 256) hbuf[b*HH + v] = h_last;
}

// ---------------- final FC: out = relu(relu(h_T) @ Wfc + bfc) ---------------
__global__ __launch_bounds__(256) void final_fc_kernel(
    const float* __restrict__ hbuf, const float* __restrict__ Wfc,
    const float* __restrict__ bfc, float* __restrict__ out)
{
    int idx = blockIdx.x*256 + threadIdx.x;
    if (idx >= BB*N2) return;
    int b = idx / N2, j = idx - b*N2;
    const float* h = hbuf + b*HH;
    float o = bfc[j];
    for (int k = 0; k < HH; ++k) o += fmaxf(h[k], 0.f) * Wfc[(long)k*N2 + j];
    out[idx] = relu_(o);
}

extern "C" void kernel_launch(void* const* d_in, const int* in_sizes, int n_in,
                              void* d_out, int out_size, void* d_ws, size_t ws_size,
                              hipStream_t stream) {
    const float* nf     = (const float*)d_in[0];
    const int*   esrc   = (const int*)d_in[1];
    const int*   edst   = (const int*)d_in[2];
    const float* ew     = (const float*)d_in[3];
    const float* infect = (const float*)d_in[4];
    const float* temp   = (const float*)d_in[5];
    const float* h0     = (const float*)d_in[6];
    const float* c0     = (const float*)d_in[7];
    const float* Wg1    = (const float*)d_in[8];
    const float* bg1    = (const float*)d_in[9];
    const float* Wg2    = (const float*)d_in[10];
    const float* bg2    = (const float*)d_in[11];
    const float* Wgfc   = (const float*)d_in[12];
    const float* bgfc   = (const float*)d_in[13];
    const float* Wi1    = (const float*)d_in[14];
    const float* bi1    = (const float*)d_in[15];
    const float* Wi2    = (const float*)d_in[16];
    const float* bi2    = (const float*)d_in[17];
    const float* Wi3    = (const float*)d_in[18];
    const float* bi3    = (const float*)d_in[19];
    const float* Wi4    = (const float*)d_in[20];
    const float* bi4    = (const float*)d_in[21];
    const float* Wt1    = (const float*)d_in[22];
    const float* bt1    = (const float*)d_in[23];
    const float* Wt2    = (const float*)d_in[24];
    const float* bt2    = (const float*)d_in[25];
    const float* Wcat   = (const float*)d_in[26];
    const float* bcat   = (const float*)d_in[27];
    const float* Wih    = (const float*)d_in[28];
    const float* Whh    = (const float*)d_in[29];
    const float* bih    = (const float*)d_in[30];
    const float* bhh    = (const float*)d_in[31];
    const float* Wfc    = (const float*)d_in[32];
    const float* bfc    = (const float*)d_in[33];

    char* ws = (char*)d_ws;
    size_t off = 0;
    __hip_bfloat16* x2g = (__hip_bfloat16*)(ws + off); off += (size_t)BT*K2*2;
    __hip_bfloat16* WgfcT = (__hip_bfloat16*)(ws + off); off += (size_t)II*K2*2;
    float* g_pre = (float*)(ws + off); off += (size_t)BT*II*4;
    float* infb  = (float*)(ws + off); off += (size_t)BT*II*4;
    float* tpb   = (float*)(ws + off); off += (size_t)BT*II*4;
    float* xg    = (float*)(ws + off); off += (size_t)BT*1024*4;
    float* hbuf  = (float*)(ws + off); off += (size_t)BB*HH*4;
    h8* wreg8 = (h8*)(ws + off); off += (size_t)WREG8*16;
    h8* wlds8 = (h8*)(ws + off); off += (size_t)WLDS8*16;

    pack_whh_kernel<<<128, 256, 0, stream>>>(Whh, wreg8, wlds8);
    packT_kernel<<<GNT, 256, 0, stream>>>(Wgfc, WgfcT);
    gcn_kernel<<<BT, 256, 0, stream>>>(nf, esrc, edst, ew, Wg1, bg1, Wg2, bg2, x2g);
    branches_kernel<<<BT/16, 256, 0, stream>>>(infect, temp, Wi1, bi1, Wi2, bi2,
                                               Wi3, bi3, Wi4, bi4, Wt1, bt1, Wt2, bt2,
                                               infb, tpb);
    gemm_kernel<<<BT/GBM, 512, 0, stream>>>(x2g, WgfcT, g_pre);
    li_xg_kernel<<<BT/16, 256, 0, stream>>>(g_pre, bgfc, infb, tpb, Wcat, bcat,
                                            Wih, bih, bhh, xg);
    lstm_kernel<<<BB, 512, 0, stream>>>(xg, wreg8, wlds8, h0, c0, hbuf);
    final_fc_kernel<<<(BB*N2 + 255)/256, 256, 0, stream>>>(hbuf, Wfc, bfc, (float*)d_out);
}

// Round 5
// 738.958 us; speedup vs baseline: 1.1388x; 1.1388x over previous
//
#include <hip/hip_runtime.h>
#include <hip/hip_bf16.h>

#define BB 8
#define TT 168
#define NN 425
#define EE 2048
#define II 128
#define HH 256
#define F1 10
#define F2 32
#define BT (BB*TT)       // 1344
#define K2 (NN*F2)       // 13600
#define N2 (2*NN)        // 850

// LSTM: 512 thr/block (8 waves, 1 block/CU -> 2 waves/SIMD -> 256 VGPR cap).
// Thread owns 2 rows of Whh (fp16). Per row: 104 h2 in VGPRs (2x104=208
// regs), 24 h2 in LDS (96 KB/block). h broadcast via readlane.
#define RJ2 104                 // h2 per row in registers (k2 in [0,104))
#define RJ8 26                  // h8 chunks per row in regs
#define LCC 6                   // h8 chunks per row in LDS
#define WREG8 (512*2*RJ8)       // 26624 h8
#define WLDS8 (2*LCC*512)       // 6144 h8 = 96 KB

typedef _Float16 h2 __attribute__((ext_vector_type(2)));
typedef _Float16 h8 __attribute__((ext_vector_type(8)));
typedef short bf16x8 __attribute__((ext_vector_type(8)));
typedef float f32x4 __attribute__((ext_vector_type(4)));

__device__ __forceinline__ float relu_(float x){ return fmaxf(x, 0.f); }
__device__ __forceinline__ float sigmoid_(float x){ return 1.f/(1.f + expf(-x)); }
__device__ __forceinline__ float dot2_(h2 a, h2 b, float c){
#if __has_builtin(__builtin_amdgcn_fdot2)
    return __builtin_amdgcn_fdot2(a, b, c, false);
#else
    return c + (float)a[0]*(float)b[0] + (float)a[1]*(float)b[1];
#endif
}

// ---------------- GCN: two layers fused, one block per (b,t) graph ----------
__global__ __launch_bounds__(256) void gcn_kernel(
    const float* __restrict__ nf, const int* __restrict__ esrc,
    const int* __restrict__ edst, const float* __restrict__ ew,
    const float* __restrict__ Wg1, const float* __restrict__ bg1,
    const float* __restrict__ Wg2, const float* __restrict__ bg2,
    __hip_bfloat16* __restrict__ x2g)
{
    __shared__ float xs[NN];
    __shared__ float dinv[NN];
    __shared__ float agg1[NN];
    __shared__ float nrm[EE];
    __shared__ float x1[NN*F1];
    __shared__ float agg2[NN*F1];
    __shared__ float wg1s[F1], bg1s[F1], wg2s[F1*F2], bg2s[F2];

    const int bt = blockIdx.x, tid = threadIdx.x;
    const long eb = (long)bt * EE;

    for (int v = tid; v < NN; v += 256) {
        xs[v] = nf[(long)bt*NN + v];
        dinv[v] = 1.0f;
        agg1[v] = 0.f;
    }
    for (int i = tid; i < NN*F1; i += 256) agg2[i] = 0.f;
    if (tid < F1) { wg1s[tid] = Wg1[tid]; bg1s[tid] = bg1[tid]; }
    if (tid < F2) bg2s[tid] = bg2[tid];
    for (int i = tid; i < F1*F2; i += 256) wg2s[i] = Wg2[i];
    __syncthreads();

    for (int e = tid; e < EE; e += 256)
        atomicAdd(&dinv[edst[eb+e]], ew[eb+e]);
    __syncthreads();
    for (int v = tid; v < NN; v += 256) {
        float dg = dinv[v];
        dinv[v] = dg > 0.f ? 1.0f / sqrtf(fmaxf(dg, 1e-12f)) : 0.f;
    }
    __syncthreads();

    for (int e = tid; e < EE; e += 256) {
        int s = esrc[eb+e], d = edst[eb+e];
        float nm = dinv[s] * ew[eb+e] * dinv[d];
        nrm[e] = nm;
        atomicAdd(&agg1[d], nm * xs[s]);
    }
    __syncthreads();
    for (int v = tid; v < NN; v += 256) agg1[v] += dinv[v]*dinv[v]*xs[v];
    __syncthreads();
    for (int i = tid; i < NN*F1; i += 256) {
        int v = i / F1, f = i - v*F1;
        x1[i] = relu_(agg1[v] * wg1s[f] + bg1s[f]);
    }
    __syncthreads();

    for (int e = tid; e < EE; e += 256) {
        int s = esrc[eb+e], d = edst[eb+e];
        float nm = nrm[e];
        #pragma unroll
        for (int f = 0; f < F1; ++f)
            atomicAdd(&agg2[d*F1+f], nm * x1[s*F1+f]);
    }
    __syncthreads();
    for (int i = tid; i < NN*F1; i += 256) {
        int v = i / F1;
        agg2[i] += dinv[v]*dinv[v]*x1[i];
    }
    __syncthreads();

    for (int i = tid; i < NN*F2; i += 256) {
        int v = i >> 5, k = i & 31;
        float o = bg2s[k];
        #pragma unroll
        for (int f = 0; f < F1; ++f) o += agg2[v*F1+f] * wg2s[f*F2+k];
        x2g[(long)bt*K2 + i] = __float2bfloat16(relu_(o));
    }
}

// ---------------- transpose-pack Wgfc fp32 [13600,128] -> bf16 [128,13600] --
__global__ __launch_bounds__(256) void packT_kernel(
    const float* __restrict__ W, __hip_bfloat16* __restrict__ out)
{
    __shared__ float tile[64][129];
    const int k0 = blockIdx.x * 64, tid = threadIdx.x;
    for (int i = tid; i < 64*128; i += 256) {
        int r = i >> 7, j = i & 127;
        tile[r][j] = (k0 + r < K2) ? W[(size_t)(k0+r)*II + j] : 0.f;
    }
    __syncthreads();
    for (int i = tid; i < 64*128; i += 256) {
        int j = i >> 6, r = i & 63;
        if (k0 + r < K2) out[(size_t)j*K2 + k0 + r] = __float2bfloat16(tile[r][j]);
    }
}

// ---------------- MFMA bf16 GEMM, split-K: g_pre += x2 @ Wgfc ---------------
// A [1344,13600] bf16; Bt = Wgfc^T [128,13600] bf16. 8 K-chunks x 21 M-tiles.
#define GBM 64
#define GBK 64
#define GCH 8
#define GST 27    // BK-steps per chunk; 8*27*64 = 13824 >= 13600 (guarded)
__global__ __launch_bounds__(256) void gemm_kernel(
    const __hip_bfloat16* __restrict__ A, const __hip_bfloat16* __restrict__ Bt,
    float* __restrict__ C)
{
    __shared__ __align__(16) char As[2][GBM*GBK*2];    // 8 KB x2
    __shared__ __align__(16) char Bs[2][II*GBK*2];     // 16 KB x2
    const int tid = threadIdx.x;
    const int row0 = blockIdx.x * GBM;
    const int kbeg = blockIdx.y * (GST*GBK);
    const int wave = tid >> 6, lane = tid & 63;
    const int wm = wave >> 1, wn = wave & 1;           // wave tile 32M x 64N
    const int l16 = lane & 15, lk = lane >> 4;
    const short* Aa = (const short*)A;
    const short* Bb = (const short*)Bt;

    const int ar = tid >> 2, ac = tid & 3;        // A: row 0..63, 2 h8 each
    const int bc = tid >> 1, bh = (tid & 1) * 4;  // B: col 0..127, 4 h8 each

    f32x4 acc[2][4];
    #pragma unroll
    for (int m = 0; m < 2; ++m)
        #pragma unroll
        for (int n = 0; n < 4; ++n) acc[m][n] = (f32x4){0.f,0.f,0.f,0.f};

    // stage step 0
    {
        #pragma unroll
        for (int j = 0; j < 2; ++j) {
            bf16x8 va = {0,0,0,0,0,0,0,0};
            int k = kbeg + ac*16 + j*8;
            if (k < K2) va = *(const bf16x8*)(Aa + (size_t)(row0+ar)*K2 + k);
            *(bf16x8*)(&As[0][0] + ((ar*128 + (ac*2+j)*16) ^ ((ar&7)<<4))) = va;
        }
        #pragma unroll
        for (int j = 0; j < 4; ++j) {
            bf16x8 vb = {0,0,0,0,0,0,0,0};
            int k = kbeg + (bh+j)*8;
            if (k < K2) vb = *(const bf16x8*)(Bb + (size_t)bc*K2 + k);
            *(bf16x8*)(&Bs[0][0] + ((bc*128 + (bh+j)*16) ^ ((bc&7)<<4))) = vb;
        }
    }
    __syncthreads();

    for (int s = 0; s < GST; ++s) {
        const int d = s & 1;
        bf16x8 pa[2], pb[4];
        #pragma unroll
        for (int j = 0; j < 2; ++j) pa[j] = (bf16x8){0,0,0,0,0,0,0,0};
        #pragma unroll
        for (int j = 0; j < 4; ++j) pb[j] = (bf16x8){0,0,0,0,0,0,0,0};
        if (s + 1 < GST) {
            int k0n = kbeg + (s+1)*GBK;
            #pragma unroll
            for (int j = 0; j < 2; ++j) {
                int k = k0n + ac*16 + j*8;
                if (k < K2) pa[j] = *(const bf16x8*)(Aa + (size_t)(row0+ar)*K2 + k);
            }
            #pragma unroll
            for (int j = 0; j < 4; ++j) {
                int k = k0n + (bh+j)*8;
                if (k < K2) pb[j] = *(const bf16x8*)(Bb + (size_t)bc*K2 + k);
            }
        }
        #pragma unroll
        for (int s2 = 0; s2 < 2; ++s2) {
            bf16x8 af[2], bf[4];
            #pragma unroll
            for (int m = 0; m < 2; ++m) {
                int row = wm*32 + m*16 + l16;
                af[m] = *(const bf16x8*)(&As[d][0] + ((row*128 + s2*64 + lk*16) ^ ((row&7)<<4)));
            }
            #pragma unroll
            for (int n = 0; n < 4; ++n) {
                int col = wn*64 + n*16 + l16;
                bf[n] = *(const bf16x8*)(&Bs[d][0] + ((col*128 + s2*64 + lk*16) ^ ((col&7)<<4)));
            }
            #pragma unroll
            for (int m = 0; m < 2; ++m)
                #pragma unroll
                for (int n = 0; n < 4; ++n)
                    acc[m][n] = __builtin_amdgcn_mfma_f32_16x16x32_bf16(af[m], bf[n], acc[m][n], 0, 0, 0);
        }
        if (s + 1 < GST) {
            #pragma unroll
            for (int j = 0; j < 2; ++j)
                *(bf16x8*)(&As[d^1][0] + ((ar*128 + (ac*2+j)*16) ^ ((ar&7)<<4))) = pa[j];
            #pragma unroll
            for (int j = 0; j < 4; ++j)
                *(bf16x8*)(&Bs[d^1][0] + ((bc*128 + (bh+j)*16) ^ ((bc&7)<<4))) = pb[j];
        }
        __syncthreads();
    }

    #pragma unroll
    for (int m = 0; m < 2; ++m)
        #pragma unroll
        for (int n = 0; n < 4; ++n)
            #pragma unroll
            for (int q = 0; q < 4; ++q)
                atomicAdd(&C[(size_t)(row0 + wm*32 + m*16 + lk*4 + q)*II + wn*64 + n*16 + l16],
                          acc[m][n][q]);
}

// ---------------- infect & temp MLP branches (16 rows per block) ------------
__global__ __launch_bounds__(256) void branches_kernel(
    const float* __restrict__ infect, const float* __restrict__ temp,
    const float* __restrict__ Wi1, const float* __restrict__ bi1,
    const float* __restrict__ Wi2, const float* __restrict__ bi2,
    const float* __restrict__ Wi3, const float* __restrict__ bi3,
    const float* __restrict__ Wi4, const float* __restrict__ bi4,
    const float* __restrict__ Wt1, const float* __restrict__ bt1,
    const float* __restrict__ Wt2, const float* __restrict__ bt2,
    float* __restrict__ infout, float* __restrict__ tpout)
{
    __shared__ float inA[16*25], inT[16*13];
    __shared__ float bufA[16*II], bufB[16*II];
    const int r0 = blockIdx.x * 16, tid = threadIdx.x;

    for (int i = tid; i < 16*25; i += 256) { int r=i/25,k=i-r*25; inA[i] = infect[(long)(r0+r)*25+k]; }
    for (int i = tid; i < 16*13; i += 256) { int r=i/13,k=i-r*13; inT[i] = temp[(long)(r0+r)*13+k]; }
    __syncthreads();
    for (int i = tid; i < 16*II; i += 256) { int r=i>>7,u=i&127; float o=bi1[u];
        for (int k=0;k<25;++k) o += inA[r*25+k]*Wi1[k*II+u];
        bufA[i]=relu_(o); }
    __syncthreads();
    for (int i = tid; i < 16*II; i += 256) { int r=i>>7,u=i&127; float o=bi2[u];
        for (int k=0;k<II;++k) o += bufA[r*II+k]*Wi2[k*II+u];
        bufB[i]=relu_(o); }
    __syncthreads();
    for (int i = tid; i < 16*64; i += 256) { int r=i>>6,u=i&63; float o=bi3[u];
        for (int k=0;k<II;++k) o += bufB[r*II+k]*Wi3[k*64+u];
        bufA[r*64+u]=relu_(o); }
    __syncthreads();
    for (int i = tid; i < 16*II; i += 256) { int r=i>>7,u=i&127; float o=bi4[u];
        for (int k=0;k<64;++k) o += bufA[r*64+k]*Wi4[k*II+u];
        infout[(long)(r0+r)*II+u]=relu_(o); }
    for (int i = tid; i < 16*64; i += 256) { int r=i>>6,u=i&63; float o=bt1[u];
        for (int k=0;k<13;++k) o += inT[r*13+k]*Wt1[k*64+u];
        bufB[r*64+u]=relu_(o); }
    __syncthreads();
    for (int i = tid; i < 16*II; i += 256) { int r=i>>7,u=i&127; float o=bt2[u];
        for (int k=0;k<64;++k) o += bufB[r*64+k]*Wt2[k*II+u];
        tpout[(long)(r0+r)*II+u]=relu_(o); }
}

// ---------------- li = relu(cat@Wcat+bcat); xg = li@Wih^T + bih + bhh -------
__global__ __launch_bounds__(256) void li_xg_kernel(
    const float* __restrict__ g_pre, const float* __restrict__ bgfc,
    const float* __restrict__ infb, const float* __restrict__ tpb,
    const float* __restrict__ Wcat, const float* __restrict__ bcat,
    const float* __restrict__ Wih, const float* __restrict__ bih,
    const float* __restrict__ bhh, float* __restrict__ xg)
{
    __shared__ float cat[16*384];
    __shared__ __align__(16) float li[16*II];
    const int r0 = blockIdx.x * 16, tid = threadIdx.x;

    for (int i = tid; i < 16*II; i += 256) {
        int r = i>>7, u = i&127;
        cat[r*384 + u]       = relu_(g_pre[(long)(r0+r)*II+u] + bgfc[u]);
        cat[r*384 + 128 + u] = infb[(long)(r0+r)*II+u];
        cat[r*384 + 256 + u] = tpb[(long)(r0+r)*II+u];
    }
    __syncthreads();
    {
        int u = tid & 127, rh = tid >> 7;
        float acc[8];
        #pragma unroll
        for (int x = 0; x < 8; ++x) acc[x] = bcat[u];
        for (int k = 0; k < 384; ++k) {
            float w = Wcat[k*II+u];
            #pragma unroll
            for (int x = 0; x < 8; ++x) acc[x] += cat[(rh*8+x)*384 + k] * w;
        }
        #pragma unroll
        for (int x = 0; x < 8; ++x) li[(rh*8+x)*II + u] = relu_(acc[x]);
    }
    __syncthreads();
    for (int jj = 0; jj < 4; ++jj) {
        int j = tid + jj*256;
        float bb = bih[j] + bhh[j];
        float acc[16];
        #pragma unroll
        for (int r = 0; r < 16; ++r) acc[r] = bb;
        for (int k4 = 0; k4 < 32; ++k4) {
            float4 wv = *(const float4*)&Wih[(long)j*II + k4*4];
            #pragma unroll
            for (int r = 0; r < 16; ++r) {
                float4 lv = *(const float4*)&li[r*II + k4*4];
                acc[r] += wv.x*lv.x + wv.y*lv.y + wv.z*lv.z + wv.w*lv.w;
            }
        }
        #pragma unroll
        for (int r = 0; r < 16; ++r) xg[(long)(r0+r)*1024 + j] = acc[r];
    }
}

// ---------------- pack Whh fp32 -> fp16 register/LDS layouts ----------------
// Thread u owns rows R0=(u>>8)*512+(u&255), R0+256.
// wreg8[u*52 + r*26 + m]  : h8 = k2 range [4m, 4m+4)       (m < 26)
// wlds8[(r*6+c)*512 + u]  : h8 = k2 range [104+4c, ...+4)  (c < 6)
__global__ __launch_bounds__(256) void pack_whh_kernel(
    const float* __restrict__ Whh, h8* __restrict__ wreg8,
    h8* __restrict__ wlds8)
{
    int i = blockIdx.x*256 + threadIdx.x;   // grid 128 blocks -> 32768 items
    int row, k2base;
    bool isreg = (i < WREG8);
    if (isreg) {
        int u = i / 52, rem = i % 52, r = rem / 26, m = rem % 26;
        row = ((u>>8)*2 + r)*256 + (u&255);
        k2base = m*4;
    } else {
        int L = i - WREG8;
        int u = L & 511, rc = L >> 9, c = rc % LCC, r = rc / LCC;
        row = ((u>>8)*2 + r)*256 + (u&255);
        k2base = RJ2 + c*4;
    }
    h8 v;
    #pragma unroll
    for (int q = 0; q < 4; ++q) {
        v[2*q]   = (_Float16)Whh[(long)row*HH + 2*(k2base+q)];
        v[2*q+1] = (_Float16)Whh[(long)row*HH + 2*(k2base+q) + 1];
    }
    if (isreg) wreg8[i] = v; else wlds8[i - WREG8] = v;
}

// ---------------- LSTM: 1 block/batch, reg-resident Whh, readlane h bcast ---
__global__ __launch_bounds__(512, 1) void lstm_kernel(
    const float* __restrict__ xg, const h8* __restrict__ wreg8,
    const h8* __restrict__ wlds8, const float* __restrict__ h0,
    const float* __restrict__ c0, float* __restrict__ hbuf)
{
    const int u = threadIdx.x;
    const int v = u & 255;
    const int lane = u & 63;
    const int b = blockIdx.x;
    const int R0 = (u >> 8)*512 + v;

    __shared__ __align__(16) _Float16 harr[2][HH];
    __shared__ __align__(16) h8 wlds[WLDS8];     // 96 KB
    __shared__ float2 gex[256];

    for (int i = u; i < WLDS8; i += 512) wlds[i] = wlds8[i];

    h8 wreg[2*RJ8];                              // 52 h8 = 208 VGPRs
    {
        const h8* wp = wreg8 + (size_t)u * (2*RJ8);
        #pragma unroll
        for (int m = 0; m < 2*RJ8; ++m) wreg[m] = wp[m];
        #pragma unroll
        for (int m = 0; m < 2*RJ8; ++m) {
            float4 tmp = __builtin_bit_cast(float4, wreg[m]);
            asm volatile("" : "+v"(tmp.x), "+v"(tmp.y), "+v"(tmp.z), "+v"(tmp.w));
            wreg[m] = __builtin_bit_cast(h8, tmp);
        }
    }

    float c = 0.f;
    if (u < 256) { c = c0[b*HH + v]; harr[0][v] = (_Float16)h0[b*HH + v]; }
    __syncthreads();

    const float* xgb = xg + (size_t)b*TT*1024;
    float h_last = 0.f;

    #pragma unroll 1
    for (int t = 0; t < TT; ++t) {
        const int cb = t & 1;
        float x0 = xgb[t*1024 + R0];
        float x1 = xgb[t*1024 + R0 + 256];
        unsigned long long hv = *(const unsigned long long*)&harr[cb][4*lane];
        int hlo = (int)(unsigned int)hv;
        int hhi = (int)(hv >> 32);
        float a00 = 0.f, a01 = 0.f, a10 = 0.f, a11 = 0.f;

        // register-resident part: k2 in [0,104), lanes L = 0..51
        #pragma unroll
        for (int m = 0; m < RJ8; ++m) {
            h8 w0 = wreg[m];
            h8 w1 = wreg[RJ8 + m];
            int L = 2*m;
            h2 slo = __builtin_bit_cast(h2, __builtin_amdgcn_readlane(hlo, L));
            h2 shi = __builtin_bit_cast(h2, __builtin_amdgcn_readlane(hhi, L));
            a00 = dot2_(__builtin_shufflevector(w0, w0, 0, 1), slo, a00);
            a01 = dot2_(__builtin_shufflevector(w0, w0, 2, 3), shi, a01);
            a10 = dot2_(__builtin_shufflevector(w1, w1, 0, 1), slo, a10);
            a11 = dot2_(__builtin_shufflevector(w1, w1, 2, 3), shi, a11);
            slo = __builtin_bit_cast(h2, __builtin_amdgcn_readlane(hlo, L+1));
            shi = __builtin_bit_cast(h2, __builtin_amdgcn_readlane(hhi, L+1));
            a00 = dot2_(__builtin_shufflevector(w0, w0, 4, 5), slo, a00);
            a01 = dot2_(__builtin_shufflevector(w0, w0, 6, 7), shi, a01);
            a10 = dot2_(__builtin_shufflevector(w1, w1, 4, 5), slo, a10);
            a11 = dot2_(__builtin_shufflevector(w1, w1, 6, 7), shi, a11);
        }
        // LDS part: k2 in [104,128), lanes L = 52..63 (opaque addr: no LICM)
        #pragma unroll
        for (int cc = 0; cc < LCC; ++cc) {
            unsigned off = (unsigned)((cc*512 + u) * 16);
            asm volatile("" : "+v"(off));
            h8 w0 = *(const h8*)((const char*)wlds + off);
            h8 w1 = *(const h8*)((const char*)wlds + off + LCC*512*16);
            int L = 52 + 2*cc;
            h2 slo = __builtin_bit_cast(h2, __builtin_amdgcn_readlane(hlo, L));
            h2 shi = __builtin_bit_cast(h2, __builtin_amdgcn_readlane(hhi, L));
            a00 = dot2_(__builtin_shufflevector(w0, w0, 0, 1), slo, a00);
            a01 = dot2_(__builtin_shufflevector(w0, w0, 2, 3), shi, a01);
            a10 = dot2_(__builtin_shufflevector(w1, w1, 0, 1), slo, a10);
            a11 = dot2_(__builtin_shufflevector(w1, w1, 2, 3), shi, a11);
            slo = __builtin_bit_cast(h2, __builtin_amdgcn_readlane(hlo, L+1));
            shi = __builtin_bit_cast(h2, __builtin_amdgcn_readlane(hhi, L+1));
            a00 = dot2_(__builtin_shufflevector(w0, w0, 4, 5), slo, a00);
            a01 = dot2_(__builtin_shufflevector(w0, w0, 6, 7), shi, a01);
            a10 = dot2_(__builtin_shufflevector(w1, w1, 4, 5), slo, a10);
            a11 = dot2_(__builtin_shufflevector(w1, w1, 6, 7), shi, a11);
        }

        float g0 = a00 + a01 + x0;   // i (u<256) / g (u>=256)
        float g1 = a10 + a11 + x1;   // f (u<256) / o (u>=256)
        if (u >= 256) gex[v] = make_float2(g0, g1);
        __syncthreads();
        if (u < 256) {
            float2 ggo = gex[v];
            c = sigmoid_(g1)*c + sigmoid_(g0)*tanhf(ggo.x);
            float h = sigmoid_(ggo.y)*tanhf(c);
            harr[cb^1][v] = (_Float16)h;
            h_last = h;
        }
        __syncthreads();
    }
    if (u < 256) hbuf[b*HH + v] = h_last;
}

// ---------------- final FC: out = relu(relu(h_T) @ Wfc + bfc) ---------------
__global__ __launch_bounds__(256) void final_fc_kernel(
    const float* __restrict__ hbuf, const float* __restrict__ Wfc,
    const float* __restrict__ bfc, float* __restrict__ out)
{
    int idx = blockIdx.x*256 + threadIdx.x;
    if (idx >= BB*N2) return;
    int b = idx / N2, j = idx - b*N2;
    const float* h = hbuf + b*HH;
    float o = bfc[j];
    for (int k = 0; k < HH; ++k) o += fmaxf(h[k], 0.f) * Wfc[(long)k*N2 + j];
    out[idx] = relu_(o);
}

extern "C" void kernel_launch(void* const* d_in, const int* in_sizes, int n_in,
                              void* d_out, int out_size, void* d_ws, size_t ws_size,
                              hipStream_t stream) {
    const float* nf     = (const float*)d_in[0];
    const int*   esrc   = (const int*)d_in[1];
    const int*   edst   = (const int*)d_in[2];
    const float* ew     = (const float*)d_in[3];
    const float* infect = (const float*)d_in[4];
    const float* temp   = (const float*)d_in[5];
    const float* h0     = (const float*)d_in[6];
    const float* c0     = (const float*)d_in[7];
    const float* Wg1    = (const float*)d_in[8];
    const float* bg1    = (const float*)d_in[9];
    const float* Wg2    = (const float*)d_in[10];
    const float* bg2    = (const float*)d_in[11];
    const float* Wgfc   = (const float*)d_in[12];
    const float* bgfc   = (const float*)d_in[13];
    const float* Wi1    = (const float*)d_in[14];
    const float* bi1    = (const float*)d_in[15];
    const float* Wi2    = (const float*)d_in[16];
    const float* bi2    = (const float*)d_in[17];
    const float* Wi3    = (const float*)d_in[18];
    const float* bi3    = (const float*)d_in[19];
    const float* Wi4    = (const float*)d_in[20];
    const float* bi4    = (const float*)d_in[21];
    const float* Wt1    = (const float*)d_in[22];
    const float* bt1    = (const float*)d_in[23];
    const float* Wt2    = (const float*)d_in[24];
    const float* bt2    = (const float*)d_in[25];
    const float* Wcat   = (const float*)d_in[26];
    const float* bcat   = (const float*)d_in[27];
    const float* Wih    = (const float*)d_in[28];
    const float* Whh    = (const float*)d_in[29];
    const float* bih    = (const float*)d_in[30];
    const float* bhh    = (const float*)d_in[31];
    const float* Wfc    = (const float*)d_in[32];
    const float* bfc    = (const float*)d_in[33];

    char* ws = (char*)d_ws;
    size_t off = 0;
    __hip_bfloat16* x2g = (__hip_bfloat16*)(ws + off); off += (size_t)BT*K2*2;
    __hip_bfloat16* WgfcT = (__hip_bfloat16*)(ws + off); off += (size_t)II*K2*2;
    float* g_pre = (float*)(ws + off); off += (size_t)BT*II*4;
    float* infb  = (float*)(ws + off); off += (size_t)BT*II*4;
    float* tpb   = (float*)(ws + off); off += (size_t)BT*II*4;
    float* xg    = (float*)(ws + off); off += (size_t)BT*1024*4;
    float* hbuf  = (float*)(ws + off); off += (size_t)BB*HH*4;
    h8* wreg8 = (h8*)(ws + off); off += (size_t)WREG8*16;
    h8* wlds8 = (h8*)(ws + off); off += (size_t)WLDS8*16;

    hipMemsetAsync(g_pre, 0, (size_t)BT*II*4, stream);

    pack_whh_kernel<<<128, 256, 0, stream>>>(Whh, wreg8, wlds8);
    packT_kernel<<<(K2 + 63)/64, 256, 0, stream>>>(Wgfc, WgfcT);
    gcn_kernel<<<BT, 256, 0, stream>>>(nf, esrc, edst, ew, Wg1, bg1, Wg2, bg2, x2g);
    branches_kernel<<<BT/16, 256, 0, stream>>>(infect, temp, Wi1, bi1, Wi2, bi2,
                                               Wi3, bi3, Wi4, bi4, Wt1, bt1, Wt2, bt2,
                                               infb, tpb);
    gemm_kernel<<<dim3(BT/GBM, GCH), 256, 0, stream>>>(x2g, WgfcT, g_pre);
    li_xg_kernel<<<BT/16, 256, 0, stream>>>(g_pre, bgfc, infb, tpb, Wcat, bcat,
                                            Wih, bih, bhh, xg);
    lstm_kernel<<<BB, 512, 0, stream>>>(xg, wreg8, wlds8, h0, c0, hbuf);
    final_fc_kernel<<<(BB*N2 + 255)/256, 256, 0, stream>>>(hbuf, Wfc, bfc, (float*)d_out);
}

// Round 6
// 738.926 us; speedup vs baseline: 1.1389x; 1.0000x over previous
//
#include <hip/hip_runtime.h>
#include <hip/hip_bf16.h>

#define BB 8
#define TT 168
#define NN 425
#define EE 2048
#define II 128
#define HH 256
#define F1 10
#define F2 32
#define BT (BB*TT)       // 1344
#define K2 (NN*F2)       // 13600
#define N2 (2*NN)        // 850

// LSTM: 512 thr/block, amdgpu_waves_per_eu(2,2) -> 256-reg budget/thread.
// Thread owns 2 rows of Whh (fp16). Per row: 104 h2 in VGPRs (208 regs),
// 24 h2 in LDS (96 KB/block). h broadcast via readlane.
#define RJ2 104                 // h2 per row in registers (k2 in [0,104))
#define RJ8 26                  // h8 chunks per row in regs
#define LCC 6                   // h8 chunks per row in LDS
#define WREG8 (512*2*RJ8)       // 26624 h8
#define WLDS8 (2*LCC*512)       // 6144 h8 = 96 KB

typedef _Float16 h2 __attribute__((ext_vector_type(2)));
typedef _Float16 h8 __attribute__((ext_vector_type(8)));
typedef short bf16x8 __attribute__((ext_vector_type(8)));
typedef float f32x4 __attribute__((ext_vector_type(4)));

__device__ __forceinline__ float relu_(float x){ return fmaxf(x, 0.f); }
__device__ __forceinline__ float sigmoid_(float x){ return 1.f/(1.f + expf(-x)); }
__device__ __forceinline__ float dot2_(h2 a, h2 b, float c){
#if __has_builtin(__builtin_amdgcn_fdot2)
    return __builtin_amdgcn_fdot2(a, b, c, false);
#else
    return c + (float)a[0]*(float)b[0] + (float)a[1]*(float)b[1];
#endif
}

// ---------------- GCN: two layers fused, one block per (b,t) graph ----------
__global__ __launch_bounds__(256) void gcn_kernel(
    const float* __restrict__ nf, const int* __restrict__ esrc,
    const int* __restrict__ edst, const float* __restrict__ ew,
    const float* __restrict__ Wg1, const float* __restrict__ bg1,
    const float* __restrict__ Wg2, const float* __restrict__ bg2,
    __hip_bfloat16* __restrict__ x2g)
{
    __shared__ float xs[NN];
    __shared__ float dinv[NN];
    __shared__ float agg1[NN];
    __shared__ float nrm[EE];
    __shared__ float x1[NN*F1];
    __shared__ float agg2[NN*F1];
    __shared__ float wg1s[F1], bg1s[F1], wg2s[F1*F2], bg2s[F2];

    const int bt = blockIdx.x, tid = threadIdx.x;
    const long eb = (long)bt * EE;

    for (int v = tid; v < NN; v += 256) {
        xs[v] = nf[(long)bt*NN + v];
        dinv[v] = 1.0f;
        agg1[v] = 0.f;
    }
    for (int i = tid; i < NN*F1; i += 256) agg2[i] = 0.f;
    if (tid < F1) { wg1s[tid] = Wg1[tid]; bg1s[tid] = bg1[tid]; }
    if (tid < F2) bg2s[tid] = bg2[tid];
    for (int i = tid; i < F1*F2; i += 256) wg2s[i] = Wg2[i];
    __syncthreads();

    for (int e = tid; e < EE; e += 256)
        atomicAdd(&dinv[edst[eb+e]], ew[eb+e]);
    __syncthreads();
    for (int v = tid; v < NN; v += 256) {
        float dg = dinv[v];
        dinv[v] = dg > 0.f ? 1.0f / sqrtf(fmaxf(dg, 1e-12f)) : 0.f;
    }
    __syncthreads();

    for (int e = tid; e < EE; e += 256) {
        int s = esrc[eb+e], d = edst[eb+e];
        float nm = dinv[s] * ew[eb+e] * dinv[d];
        nrm[e] = nm;
        atomicAdd(&agg1[d], nm * xs[s]);
    }
    __syncthreads();
    for (int v = tid; v < NN; v += 256) agg1[v] += dinv[v]*dinv[v]*xs[v];
    __syncthreads();
    for (int i = tid; i < NN*F1; i += 256) {
        int v = i / F1, f = i - v*F1;
        x1[i] = relu_(agg1[v] * wg1s[f] + bg1s[f]);
    }
    __syncthreads();

    for (int e = tid; e < EE; e += 256) {
        int s = esrc[eb+e], d = edst[eb+e];
        float nm = nrm[e];
        #pragma unroll
        for (int f = 0; f < F1; ++f)
            atomicAdd(&agg2[d*F1+f], nm * x1[s*F1+f]);
    }
    __syncthreads();
    for (int i = tid; i < NN*F1; i += 256) {
        int v = i / F1;
        agg2[i] += dinv[v]*dinv[v]*x1[i];
    }
    __syncthreads();

    for (int i = tid; i < NN*F2; i += 256) {
        int v = i >> 5, k = i & 31;
        float o = bg2s[k];
        #pragma unroll
        for (int f = 0; f < F1; ++f) o += agg2[v*F1+f] * wg2s[f*F2+k];
        x2g[(long)bt*K2 + i] = __float2bfloat16(relu_(o));
    }
}

// ---------------- transpose-pack Wgfc fp32 [13600,128] -> bf16 [128,13600] --
__global__ __launch_bounds__(256) void packT_kernel(
    const float* __restrict__ W, __hip_bfloat16* __restrict__ out)
{
    __shared__ float tile[64][129];
    const int k0 = blockIdx.x * 64, tid = threadIdx.x;
    for (int i = tid; i < 64*128; i += 256) {
        int r = i >> 7, j = i & 127;
        tile[r][j] = (k0 + r < K2) ? W[(size_t)(k0+r)*II + j] : 0.f;
    }
    __syncthreads();
    for (int i = tid; i < 64*128; i += 256) {
        int j = i >> 6, r = i & 63;
        if (k0 + r < K2) out[(size_t)j*K2 + k0 + r] = __float2bfloat16(tile[r][j]);
    }
}

// ---------------- MFMA bf16 GEMM, split-K: g_pre += x2 @ Wgfc ---------------
// A [1344,13600] bf16; Bt = Wgfc^T [128,13600] bf16. 8 K-chunks x 21 M-tiles.
#define GBM 64
#define GBK 64
#define GCH 8
#define GST 27    // BK-steps per chunk; 8*27*64 = 13824 >= 13600 (guarded)
__global__ __launch_bounds__(256) void gemm_kernel(
    const __hip_bfloat16* __restrict__ A, const __hip_bfloat16* __restrict__ Bt,
    float* __restrict__ C)
{
    __shared__ __align__(16) char As[2][GBM*GBK*2];    // 8 KB x2
    __shared__ __align__(16) char Bs[2][II*GBK*2];     // 16 KB x2
    const int tid = threadIdx.x;
    const int row0 = blockIdx.x * GBM;
    const int kbeg = blockIdx.y * (GST*GBK);
    const int wave = tid >> 6, lane = tid & 63;
    const int wm = wave >> 1, wn = wave & 1;           // wave tile 32M x 64N
    const int l16 = lane & 15, lk = lane >> 4;
    const short* Aa = (const short*)A;
    const short* Bb = (const short*)Bt;

    const int ar = tid >> 2, ac = tid & 3;        // A: row 0..63, 2 h8 each
    const int bc = tid >> 1, bh = (tid & 1) * 4;  // B: col 0..127, 4 h8 each

    f32x4 acc[2][4];
    #pragma unroll
    for (int m = 0; m < 2; ++m)
        #pragma unroll
        for (int n = 0; n < 4; ++n) acc[m][n] = (f32x4){0.f,0.f,0.f,0.f};

    // stage step 0
    {
        #pragma unroll
        for (int j = 0; j < 2; ++j) {
            bf16x8 va = {0,0,0,0,0,0,0,0};
            int k = kbeg + ac*16 + j*8;
            if (k < K2) va = *(const bf16x8*)(Aa + (size_t)(row0+ar)*K2 + k);
            *(bf16x8*)(&As[0][0] + ((ar*128 + (ac*2+j)*16) ^ ((ar&7)<<4))) = va;
        }
        #pragma unroll
        for (int j = 0; j < 4; ++j) {
            bf16x8 vb = {0,0,0,0,0,0,0,0};
            int k = kbeg + (bh+j)*8;
            if (k < K2) vb = *(const bf16x8*)(Bb + (size_t)bc*K2 + k);
            *(bf16x8*)(&Bs[0][0] + ((bc*128 + (bh+j)*16) ^ ((bc&7)<<4))) = vb;
        }
    }
    __syncthreads();

    for (int s = 0; s < GST; ++s) {
        const int d = s & 1;
        bf16x8 pa[2], pb[4];
        #pragma unroll
        for (int j = 0; j < 2; ++j) pa[j] = (bf16x8){0,0,0,0,0,0,0,0};
        #pragma unroll
        for (int j = 0; j < 4; ++j) pb[j] = (bf16x8){0,0,0,0,0,0,0,0};
        if (s + 1 < GST) {
            int k0n = kbeg + (s+1)*GBK;
            #pragma unroll
            for (int j = 0; j < 2; ++j) {
                int k = k0n + ac*16 + j*8;
                if (k < K2) pa[j] = *(const bf16x8*)(Aa + (size_t)(row0+ar)*K2 + k);
            }
            #pragma unroll
            for (int j = 0; j < 4; ++j) {
                int k = k0n + (bh+j)*8;
                if (k < K2) pb[j] = *(const bf16x8*)(Bb + (size_t)bc*K2 + k);
            }
        }
        #pragma unroll
        for (int s2 = 0; s2 < 2; ++s2) {
            bf16x8 af[2], bf[4];
            #pragma unroll
            for (int m = 0; m < 2; ++m) {
                int row = wm*32 + m*16 + l16;
                af[m] = *(const bf16x8*)(&As[d][0] + ((row*128 + s2*64 + lk*16) ^ ((row&7)<<4)));
            }
            #pragma unroll
            for (int n = 0; n < 4; ++n) {
                int col = wn*64 + n*16 + l16;
                bf[n] = *(const bf16x8*)(&Bs[d][0] + ((col*128 + s2*64 + lk*16) ^ ((col&7)<<4)));
            }
            #pragma unroll
            for (int m = 0; m < 2; ++m)
                #pragma unroll
                for (int n = 0; n < 4; ++n)
                    acc[m][n] = __builtin_amdgcn_mfma_f32_16x16x32_bf16(af[m], bf[n], acc[m][n], 0, 0, 0);
        }
        if (s + 1 < GST) {
            #pragma unroll
            for (int j = 0; j < 2; ++j)
                *(bf16x8*)(&As[d^1][0] + ((ar*128 + (ac*2+j)*16) ^ ((ar&7)<<4))) = pa[j];
            #pragma unroll
            for (int j = 0; j < 4; ++j)
                *(bf16x8*)(&Bs[d^1][0] + ((bc*128 + (bh+j)*16) ^ ((bc&7)<<4))) = pb[j];
        }
        __syncthreads();
    }

    #pragma unroll
    for (int m = 0; m < 2; ++m)
        #pragma unroll
        for (int n = 0; n < 4; ++n)
            #pragma unroll
            for (int q = 0; q < 4; ++q)
                atomicAdd(&C[(size_t)(row0 + wm*32 + m*16 + lk*4 + q)*II + wn*64 + n*16 + l16],
                          acc[m][n][q]);
}

// ---------------- infect & temp MLP branches (16 rows per block) ------------
__global__ __launch_bounds__(256) void branches_kernel(
    const float* __restrict__ infect, const float* __restrict__ temp,
    const float* __restrict__ Wi1, const float* __restrict__ bi1,
    const float* __restrict__ Wi2, const float* __restrict__ bi2,
    const float* __restrict__ Wi3, const float* __restrict__ bi3,
    const float* __restrict__ Wi4, const float* __restrict__ bi4,
    const float* __restrict__ Wt1, const float* __restrict__ bt1,
    const float* __restrict__ Wt2, const float* __restrict__ bt2,
    float* __restrict__ infout, float* __restrict__ tpout)
{
    __shared__ float inA[16*25], inT[16*13];
    __shared__ float bufA[16*II], bufB[16*II];
    const int r0 = blockIdx.x * 16, tid = threadIdx.x;

    for (int i = tid; i < 16*25; i += 256) { int r=i/25,k=i-r*25; inA[i] = infect[(long)(r0+r)*25+k]; }
    for (int i = tid; i < 16*13; i += 256) { int r=i/13,k=i-r*13; inT[i] = temp[(long)(r0+r)*13+k]; }
    __syncthreads();
    for (int i = tid; i < 16*II; i += 256) { int r=i>>7,u=i&127; float o=bi1[u];
        for (int k=0;k<25;++k) o += inA[r*25+k]*Wi1[k*II+u];
        bufA[i]=relu_(o); }
    __syncthreads();
    for (int i = tid; i < 16*II; i += 256) { int r=i>>7,u=i&127; float o=bi2[u];
        for (int k=0;k<II;++k) o += bufA[r*II+k]*Wi2[k*II+u];
        bufB[i]=relu_(o); }
    __syncthreads();
    for (int i = tid; i < 16*64; i += 256) { int r=i>>6,u=i&63; float o=bi3[u];
        for (int k=0;k<II;++k) o += bufB[r*II+k]*Wi3[k*64+u];
        bufA[r*64+u]=relu_(o); }
    __syncthreads();
    for (int i = tid; i < 16*II; i += 256) { int r=i>>7,u=i&127; float o=bi4[u];
        for (int k=0;k<64;++k) o += bufA[r*64+k]*Wi4[k*II+u];
        infout[(long)(r0+r)*II+u]=relu_(o); }
    for (int i = tid; i < 16*64; i += 256) { int r=i>>6,u=i&63; float o=bt1[u];
        for (int k=0;k<13;++k) o += inT[r*13+k]*Wt1[k*64+u];
        bufB[r*64+u]=relu_(o); }
    __syncthreads();
    for (int i = tid; i < 16*II; i += 256) { int r=i>>7,u=i&127; float o=bt2[u];
        for (int k=0;k<64;++k) o += bufB[r*64+k]*Wt2[k*II+u];
        tpout[(long)(r0+r)*II+u]=relu_(o); }
}

// ---------------- li = relu(cat@Wcat+bcat); xg = li@Wih^T + bih + bhh -------
__global__ __launch_bounds__(256) void li_xg_kernel(
    const float* __restrict__ g_pre, const float* __restrict__ bgfc,
    const float* __restrict__ infb, const float* __restrict__ tpb,
    const float* __restrict__ Wcat, const float* __restrict__ bcat,
    const float* __restrict__ Wih, const float* __restrict__ bih,
    const float* __restrict__ bhh, float* __restrict__ xg)
{
    __shared__ float cat[16*384];
    __shared__ __align__(16) float li[16*II];
    const int r0 = blockIdx.x * 16, tid = threadIdx.x;

    for (int i = tid; i < 16*II; i += 256) {
        int r = i>>7, u = i&127;
        cat[r*384 + u]       = relu_(g_pre[(long)(r0+r)*II+u] + bgfc[u]);
        cat[r*384 + 128 + u] = infb[(long)(r0+r)*II+u];
        cat[r*384 + 256 + u] = tpb[(long)(r0+r)*II+u];
    }
    __syncthreads();
    {
        int u = tid & 127, rh = tid >> 7;
        float acc[8];
        #pragma unroll
        for (int x = 0; x < 8; ++x) acc[x] = bcat[u];
        for (int k = 0; k < 384; ++k) {
            float w = Wcat[k*II+u];
            #pragma unroll
            for (int x = 0; x < 8; ++x) acc[x] += cat[(rh*8+x)*384 + k] * w;
        }
        #pragma unroll
        for (int x = 0; x < 8; ++x) li[(rh*8+x)*II + u] = relu_(acc[x]);
    }
    __syncthreads();
    for (int jj = 0; jj < 4; ++jj) {
        int j = tid + jj*256;
        float bb = bih[j] + bhh[j];
        float acc[16];
        #pragma unroll
        for (int r = 0; r < 16; ++r) acc[r] = bb;
        for (int k4 = 0; k4 < 32; ++k4) {
            float4 wv = *(const float4*)&Wih[(long)j*II + k4*4];
            #pragma unroll
            for (int r = 0; r < 16; ++r) {
                float4 lv = *(const float4*)&li[r*II + k4*4];
                acc[r] += wv.x*lv.x + wv.y*lv.y + wv.z*lv.z + wv.w*lv.w;
            }
        }
        #pragma unroll
        for (int r = 0; r < 16; ++r) xg[(long)(r0+r)*1024 + j] = acc[r];
    }
}

// ---------------- pack Whh fp32 -> fp16 register/LDS layouts ----------------
// Thread u owns rows R0=(u>>8)*512+(u&255), R0+256.
// wreg8[u*52 + r*26 + m]  : h8 = k2 range [4m, 4m+4)       (m < 26)
// wlds8[(r*6+c)*512 + u]  : h8 = k2 range [104+4c, ...+4)  (c < 6)
__global__ __launch_bounds__(256) void pack_whh_kernel(
    const float* __restrict__ Whh, h8* __restrict__ wreg8,
    h8* __restrict__ wlds8)
{
    int i = blockIdx.x*256 + threadIdx.x;   // grid 128 blocks -> 32768 items
    int row, k2base;
    bool isreg = (i < WREG8);
    if (isreg) {
        int u = i / 52, rem = i % 52, r = rem / 26, m = rem % 26;
        row = ((u>>8)*2 + r)*256 + (u&255);
        k2base = m*4;
    } else {
        int L = i - WREG8;
        int u = L & 511, rc = L >> 9, c = rc % LCC, r = rc / LCC;
        row = ((u>>8)*2 + r)*256 + (u&255);
        k2base = RJ2 + c*4;
    }
    h8 v;
    #pragma unroll
    for (int q = 0; q < 4; ++q) {
        v[2*q]   = (_Float16)Whh[(long)row*HH + 2*(k2base+q)];
        v[2*q+1] = (_Float16)Whh[(long)row*HH + 2*(k2base+q) + 1];
    }
    if (isreg) wreg8[i] = v; else wlds8[i - WREG8] = v;
}

// ---------------- LSTM: 1 block/batch, reg-resident Whh, readlane h bcast ---
__attribute__((amdgpu_waves_per_eu(2, 2)))
__global__ __launch_bounds__(512) void lstm_kernel(
    const float* __restrict__ xg, const h8* __restrict__ wreg8,
    const h8* __restrict__ wlds8, const float* __restrict__ h0,
    const float* __restrict__ c0, float* __restrict__ hbuf)
{
    const int u = threadIdx.x;
    const int v = u & 255;
    const int lane = u & 63;
    const int b = blockIdx.x;
    const int R0 = (u >> 8)*512 + v;

    __shared__ __align__(16) _Float16 harr[2][HH];
    __shared__ __align__(16) h8 wlds[WLDS8];     // 96 KB
    __shared__ float2 gex[256];

    for (int i = u; i < WLDS8; i += 512) wlds[i] = wlds8[i];

    h8 wreg[2*RJ8];                              // 52 h8 = 208 VGPRs
    {
        const h8* wp = wreg8 + (size_t)u * (2*RJ8);
        #pragma unroll
        for (int m = 0; m < 2*RJ8; ++m) wreg[m] = wp[m];
        #pragma unroll
        for (int m = 0; m < 2*RJ8; ++m) {
            float4 tmp = __builtin_bit_cast(float4, wreg[m]);
            asm volatile("" : "+v"(tmp.x), "+v"(tmp.y), "+v"(tmp.z), "+v"(tmp.w));
            wreg[m] = __builtin_bit_cast(h8, tmp);
        }
    }

    float c = 0.f;
    if (u < 256) { c = c0[b*HH + v]; harr[0][v] = (_Float16)h0[b*HH + v]; }
    __syncthreads();

    const float* xgb = xg + (size_t)b*TT*1024;
    float h_last = 0.f;

    #pragma unroll 1
    for (int t = 0; t < TT; ++t) {
        const int cb = t & 1;
        float x0 = xgb[t*1024 + R0];
        float x1 = xgb[t*1024 + R0 + 256];
        unsigned long long hv = *(const unsigned long long*)&harr[cb][4*lane];
        int hlo = (int)(unsigned int)hv;
        int hhi = (int)(hv >> 32);
        float a00 = 0.f, a01 = 0.f, a10 = 0.f, a11 = 0.f;

        // register-resident part: k2 in [0,104), lanes L = 0..51
        #pragma unroll
        for (int m = 0; m < RJ8; ++m) {
            h8 w0 = wreg[m];
            h8 w1 = wreg[RJ8 + m];
            int L = 2*m;
            h2 slo = __builtin_bit_cast(h2, __builtin_amdgcn_readlane(hlo, L));
            h2 shi = __builtin_bit_cast(h2, __builtin_amdgcn_readlane(hhi, L));
            a00 = dot2_(__builtin_shufflevector(w0, w0, 0, 1), slo, a00);
            a01 = dot2_(__builtin_shufflevector(w0, w0, 2, 3), shi, a01);
            a10 = dot2_(__builtin_shufflevector(w1, w1, 0, 1), slo, a10);
            a11 = dot2_(__builtin_shufflevector(w1, w1, 2, 3), shi, a11);
            slo = __builtin_bit_cast(h2, __builtin_amdgcn_readlane(hlo, L+1));
            shi = __builtin_bit_cast(h2, __builtin_amdgcn_readlane(hhi, L+1));
            a00 = dot2_(__builtin_shufflevector(w0, w0, 4, 5), slo, a00);
            a01 = dot2_(__builtin_shufflevector(w0, w0, 6, 7), shi, a01);
            a10 = dot2_(__builtin_shufflevector(w1, w1, 4, 5), slo, a10);
            a11 = dot2_(__builtin_shufflevector(w1, w1, 6, 7), shi, a11);
        }
        // LDS part: k2 in [104,128), lanes L = 52..63 (opaque addr: no LICM)
        #pragma unroll
        for (int cc = 0; cc < LCC; ++cc) {
            unsigned off = (unsigned)((cc*512 + u) * 16);
            asm volatile("" : "+v"(off));
            h8 w0 = *(const h8*)((const char*)wlds + off);
            h8 w1 = *(const h8*)((const char*)wlds + off + LCC*512*16);
            int L = 52 + 2*cc;
            h2 slo = __builtin_bit_cast(h2, __builtin_amdgcn_readlane(hlo, L));
            h2 shi = __builtin_bit_cast(h2, __builtin_amdgcn_readlane(hhi, L));
            a00 = dot2_(__builtin_shufflevector(w0, w0, 0, 1), slo, a00);
            a01 = dot2_(__builtin_shufflevector(w0, w0, 2, 3), shi, a01);
            a10 = dot2_(__builtin_shufflevector(w1, w1, 0, 1), slo, a10);
            a11 = dot2_(__builtin_shufflevector(w1, w1, 2, 3), shi, a11);
            slo = __builtin_bit_cast(h2, __builtin_amdgcn_readlane(hlo, L+1));
            shi = __builtin_bit_cast(h2, __builtin_amdgcn_readlane(hhi, L+1));
            a00 = dot2_(__builtin_shufflevector(w0, w0, 4, 5), slo, a00);
            a01 = dot2_(__builtin_shufflevector(w0, w0, 6, 7), shi, a01);
            a10 = dot2_(__builtin_shufflevector(w1, w1, 4, 5), slo, a10);
            a11 = dot2_(__builtin_shufflevector(w1, w1, 6, 7), shi, a11);
        }

        float g0 = a00 + a01 + x0;   // i (u<256) / g (u>=256)
        float g1 = a10 + a11 + x1;   // f (u<256) / o (u>=256)
        if (u >= 256) gex[v] = make_float2(g0, g1);
        __syncthreads();
        if (u < 256) {
            float2 ggo = gex[v];
            c = sigmoid_(g1)*c + sigmoid_(g0)*tanhf(ggo.x);
            float h = sigmoid_(ggo.y)*tanhf(c);
            harr[cb^1][v] = (_Float16)h;
            h_last = h;
        }
        __syncthreads();
    }
    if (u < 256) hbuf[b*HH + v] = h_last;
}

// ---------------- final FC: out = relu(relu(h_T) @ Wfc + bfc) ---------------
__global__ __launch_bounds__(256) void final_fc_kernel(
    const float* __restrict__ hbuf, const float* __restrict__ Wfc,
    const float* __restrict__ bfc, float* __restrict__ out)
{
    int idx = blockIdx.x*256 + threadIdx.x;
    if (idx >= BB*N2) return;
    int b = idx / N2, j = idx - b*N2;
    const float* h = hbuf + b*HH;
    float o = bfc[j];
    for (int k = 0; k < HH; ++k) o += fmaxf(h[k], 0.f) * Wfc[(long)k*N2 + j];
    out[idx] = relu_(o);
}

extern "C" void kernel_launch(void* const* d_in, const int* in_sizes, int n_in,
                              void* d_out, int out_size, void* d_ws, size_t ws_size,
                              hipStream_t stream) {
    const float* nf     = (const float*)d_in[0];
    const int*   esrc   = (const int*)d_in[1];
    const int*   edst   = (const int*)d_in[2];
    const float* ew     = (const float*)d_in[3];
    const float* infect = (const float*)d_in[4];
    const float* temp   = (const float*)d_in[5];
    const float* h0     = (const float*)d_in[6];
    const float* c0     = (const float*)d_in[7];
    const float* Wg1    = (const float*)d_in[8];
    const float* bg1    = (const float*)d_in[9];
    const float* Wg2    = (const float*)d_in[10];
    const float* bg2    = (const float*)d_in[11];
    const float* Wgfc   = (const float*)d_in[12];
    const float* bgfc   = (const float*)d_in[13];
    const float* Wi1    = (const float*)d_in[14];
    const float* bi1    = (const float*)d_in[15];
    const float* Wi2    = (const float*)d_in[16];
    const float* bi2    = (const float*)d_in[17];
    const float* Wi3    = (const float*)d_in[18];
    const float* bi3    = (const float*)d_in[19];
    const float* Wi4    = (const float*)d_in[20];
    const float* bi4    = (const float*)d_in[21];
    const float* Wt1    = (const float*)d_in[22];
    const float* bt1    = (const float*)d_in[23];
    const float* Wt2    = (const float*)d_in[24];
    const float* bt2    = (const float*)d_in[25];
    const float* Wcat   = (const float*)d_in[26];
    const float* bcat   = (const float*)d_in[27];
    const float* Wih    = (const float*)d_in[28];
    const float* Whh    = (const float*)d_in[29];
    const float* bih    = (const float*)d_in[30];
    const float* bhh    = (const float*)d_in[31];
    const float* Wfc    = (const float*)d_in[32];
    const float* bfc    = (const float*)d_in[33];

    char* ws = (char*)d_ws;
    size_t off = 0;
    __hip_bfloat16* x2g = (__hip_bfloat16*)(ws + off); off += (size_t)BT*K2*2;
    __hip_bfloat16* WgfcT = (__hip_bfloat16*)(ws + off); off += (size_t)II*K2*2;
    float* g_pre = (float*)(ws + off); off += (size_t)BT*II*4;
    float* infb  = (float*)(ws + off); off += (size_t)BT*II*4;
    float* tpb   = (float*)(ws + off); off += (size_t)BT*II*4;
    float* xg    = (float*)(ws + off); off += (size_t)BT*1024*4;
    float* hbuf  = (float*)(ws + off); off += (size_t)BB*HH*4;
    h8* wreg8 = (h8*)(ws + off); off += (size_t)WREG8*16;
    h8* wlds8 = (h8*)(ws + off); off += (size_t)WLDS8*16;

    hipMemsetAsync(g_pre, 0, (size_t)BT*II*4, stream);

    pack_whh_kernel<<<128, 256, 0, stream>>>(Whh, wreg8, wlds8);
    packT_kernel<<<(K2 + 63)/64, 256, 0, stream>>>(Wgfc, WgfcT);
    gcn_kernel<<<BT, 256, 0, stream>>>(nf, esrc, edst, ew, Wg1, bg1, Wg2, bg2, x2g);
    branches_kernel<<<BT/16, 256, 0, stream>>>(infect, temp, Wi1, bi1, Wi2, bi2,
                                               Wi3, bi3, Wi4, bi4, Wt1, bt1, Wt2, bt2,
                                               infb, tpb);
    gemm_kernel<<<dim3(BT/GBM, GCH), 256, 0, stream>>>(x2g, WgfcT, g_pre);
    li_xg_kernel<<<BT/16, 256, 0, stream>>>(g_pre, bgfc, infb, tpb, Wcat, bcat,
                                            Wih, bih, bhh, xg);
    lstm_kernel<<<BB, 512, 0, stream>>>(xg, wreg8, wlds8, h0, c0, hbuf);
    final_fc_kernel<<<(BB*N2 + 255)/256, 256, 0, stream>>>(hbuf, Wfc, bfc, (float*)d_out);
}